// Round 3
// baseline (572.477 us; speedup 1.0000x reference)
//
#include <hip/hip_runtime.h>
#include <math.h>

// Fused HQCNN, round 3: packed-fp32 (v_pk_fma_f32) over sample pairs.
// Block = 8 samples = 4 pairs, 256 threads; wave w owns pair w for conv2/fc1/fc2/tail.
// All intermediates pair-interleaved float2 in LDS so every FMA is a pk_fma.

typedef float v2f __attribute__((ext_vector_type(2)));
typedef float v4f __attribute__((ext_vector_type(4)));

static __device__ __forceinline__ v2f vfma2(v2f a, float w, v2f c) {
    return __builtin_elementwise_fma(a, (v2f){w, w}, c);
}
static __device__ __forceinline__ v2f vmax2(v2f a, v2f b) {
    return __builtin_elementwise_max(a, b);
}

#define XS_PAIR 1572   // floats per pair: 784*2 + 4 pad (bank decorrelation, f4-aligned)
#define P1_PAIR 580    // floats per pair: 288*2 + 4 pad
#define HB_OC   36     // floats per oc: 16*2 + 4 pad
#define HB_PAIR 576    // 16 * HB_OC
#define W2_OC   60     // floats per oc (2 x 28 padded + 4)

__global__ __launch_bounds__(256, 3)
void hqcnn_fused(const float* __restrict__ x,    // (B,1,28,28)
                 const float* __restrict__ w1,   // (2,1,5,5)
                 const float* __restrict__ b1,   // (2,)
                 const float* __restrict__ w2,   // (16,2,5,5)
                 const float* __restrict__ b2,   // (16,)
                 const float* __restrict__ fw1,  // (64,256)
                 const float* __restrict__ fb1,  // (64,)
                 const float* __restrict__ fw2,  // (2,64)
                 const float* __restrict__ fb2,  // (2,)
                 const float* __restrict__ fw3,  // (1,1)
                 const float* __restrict__ fb3,  // (1,)
                 const float* __restrict__ qp,   // (8,)
                 float* __restrict__ out)        // (B,2)
{
    __shared__ __align__(16) float xs[4 * XS_PAIR];   // 25152 B
    __shared__ __align__(16) float p1[4 * P1_PAIR];   //  9280 B
    __shared__ __align__(16) float hb[4 * HB_PAIR];   //  9216 B
    __shared__ __align__(16) float w2s[16 * W2_OC];   //  3840 B
    __shared__ float b2s[16];

    const int t = threadIdx.x;
    const long base = (long)blockIdx.x * 8;

    // ---- stage: x pair-interleaved, conv2 weights padded ----
    {
        for (int f = t; f < 1568; f += 256) {
            int q = f >> 3, sIdx = f & 7;           // q = float4 index within sample
            int p = sIdx >> 1, h = sIdx & 1;
            v4f g = ((const v4f*)(x + (base + sIdx) * 784))[q];
            float* dst = xs + p * XS_PAIR + q * 8 + h;
            dst[0] = g.x; dst[2] = g.y; dst[4] = g.z; dst[6] = g.w;
        }
        for (int f = t; f < 800; f += 256) {
            int oc = f / 50;
            int rem = f - oc * 50;
            int c = rem >= 25;
            int k = rem - c * 25;
            w2s[oc * W2_OC + c * 28 + k] = w2[f];
        }
        if (t < 16) b2s[t] = b2[t];
    }
    __syncthreads();

    // ---- conv1 + relu + pool (packed pairs): 288 jobs (pair,i,jh) ----
    {
        float w1c[50];
        #pragma unroll
        for (int i = 0; i < 50; ++i) w1c[i] = w1[i];   // wave-uniform -> SGPR
        float bb0 = b1[0], bb1 = b1[1];

        for (int f = t; f < 288; f += 256) {
            int p = f / 72;
            int r = f - p * 72;
            int i = r / 6;
            int jh = r - i * 6;
            v2f acc[16];                                // [c][a][b]
            #pragma unroll
            for (int q = 0; q < 16; ++q) acc[q] = (v2f){0.f, 0.f};
            #pragma unroll
            for (int u = 0; u < 6; ++u) {
                int rb = p * (XS_PAIR / 4) + (2 * i + u) * 14 + 2 * jh;
                v4f q0 = ((const v4f*)xs)[rb + 0];
                v4f q1 = ((const v4f*)xs)[rb + 1];
                v4f q2 = ((const v4f*)xs)[rb + 2];
                v4f q3 = ((const v4f*)xs)[rb + 3];
                v2f rr[8] = { {q0.x,q0.y},{q0.z,q0.w},{q1.x,q1.y},{q1.z,q1.w},
                              {q2.x,q2.y},{q2.z,q2.w},{q3.x,q3.y},{q3.z,q3.w} };
                #pragma unroll
                for (int a = 0; a < 2; ++a) {
                    if (a <= u && (u - a) <= 4) {
                        const int wu = u - a;
                        #pragma unroll
                        for (int c = 0; c < 2; ++c)
                            #pragma unroll
                            for (int b = 0; b < 4; ++b) {
                                v2f s0 = acc[c * 8 + a * 4 + b];
                                #pragma unroll
                                for (int v = 0; v < 5; ++v)
                                    s0 = vfma2(rr[b + v], w1c[c * 25 + wu * 5 + v], s0);
                                acc[c * 8 + a * 4 + b] = s0;
                            }
                    }
                }
            }
            #pragma unroll
            for (int c = 0; c < 2; ++c) {
                float bias = c ? bb1 : bb0;
                #pragma unroll
                for (int bb = 0; bb < 2; ++bb) {
                    v2f m = vmax2(vmax2(acc[c*8 + 2*bb],     acc[c*8 + 2*bb + 1]),
                                  vmax2(acc[c*8 + 4 + 2*bb], acc[c*8 + 4 + 2*bb + 1]));
                    m = m + (v2f){bias, bias};
                    m = vmax2(m, (v2f){0.f, 0.f});
                    ((v2f*)p1)[p * (P1_PAIR / 2) + c * 144 + i * 12 + 2 * jh + bb] = m;
                }
            }
        }
    }
    __syncthreads();

    // ---- conv2 + relu + pool (packed): 256 jobs (p=t>>6, oc, qi, qj) ----
    {
        int p = t >> 6;
        int oc = (t >> 2) & 15;
        int qi = (t >> 1) & 1;
        int qj = t & 1;
        v2f acc[16];                                    // [a][b]
        #pragma unroll
        for (int q = 0; q < 16; ++q) acc[q] = (v2f){0.f, 0.f};
        #pragma unroll
        for (int c = 0; c < 2; ++c) {
            float wv[28];
            {
                const v4f* wp = (const v4f*)w2s + oc * (W2_OC / 4) + c * 7;
                #pragma unroll
                for (int j = 0; j < 7; ++j) {
                    v4f w4 = wp[j];
                    wv[j*4+0] = w4.x; wv[j*4+1] = w4.y; wv[j*4+2] = w4.z; wv[j*4+3] = w4.w;
                }
            }
            #pragma unroll
            for (int u = 0; u < 8; ++u) {
                int rb = p * (P1_PAIR / 4) + c * 72 + (4 * qi + u) * 6 + 2 * qj;
                v4f q0 = ((const v4f*)p1)[rb + 0];
                v4f q1 = ((const v4f*)p1)[rb + 1];
                v4f q2 = ((const v4f*)p1)[rb + 2];
                v4f q3 = ((const v4f*)p1)[rb + 3];
                v2f rr[8] = { {q0.x,q0.y},{q0.z,q0.w},{q1.x,q1.y},{q1.z,q1.w},
                              {q2.x,q2.y},{q2.z,q2.w},{q3.x,q3.y},{q3.z,q3.w} };
                #pragma unroll
                for (int a = 0; a < 4; ++a) {
                    if (a <= u && (u - a) <= 4) {
                        const int wu = u - a;
                        #pragma unroll
                        for (int b = 0; b < 4; ++b) {
                            v2f s0 = acc[a * 4 + b];
                            #pragma unroll
                            for (int v = 0; v < 5; ++v)
                                s0 = vfma2(rr[b + v], wv[wu * 5 + v], s0);
                            acc[a * 4 + b] = s0;
                        }
                    }
                }
            }
        }
        float bias = b2s[oc];
        #pragma unroll
        for (int a2 = 0; a2 < 2; ++a2)
            #pragma unroll
            for (int b2i = 0; b2i < 2; ++b2i) {
                v2f m = vmax2(vmax2(acc[(2*a2)*4 + 2*b2i],     acc[(2*a2)*4 + 2*b2i + 1]),
                              vmax2(acc[(2*a2+1)*4 + 2*b2i], acc[(2*a2+1)*4 + 2*b2i + 1]));
                m = m + (v2f){bias, bias};
                m = vmax2(m, (v2f){0.f, 0.f});
                int pos = (2*qi + a2) * 4 + (2*qj + b2i);
                ((v2f*)hb)[p * (HB_PAIR / 2) + oc * (HB_OC / 2) + pos] = m;
            }
    }
    __syncthreads();

    // ---- fc1 (packed, in-register) + fc2 (wave reduce) + quantum + out ----
    {
        int p = t >> 6, k = t & 63;
        const v4f* wrow = (const v4f*)(fw1 + k * 256);
        float fb = fb1[k];
        v2f acc = (v2f){fb, fb};
        #pragma unroll 4
        for (int oc = 0; oc < 16; ++oc) {
            const v4f* hp = (const v4f*)(hb + p * HB_PAIR + oc * HB_OC);
            #pragma unroll
            for (int j = 0; j < 4; ++j) {
                v4f w4 = wrow[oc * 4 + j];
                v4f hA = hp[2 * j];         // pos 4j, 4j+1 (pairs)
                v4f hB = hp[2 * j + 1];     // pos 4j+2, 4j+3
                acc = vfma2((v2f){hA.x, hA.y}, w4.x, acc);
                acc = vfma2((v2f){hA.z, hA.w}, w4.y, acc);
                acc = vfma2((v2f){hB.x, hB.y}, w4.z, acc);
                acc = vfma2((v2f){hB.z, hB.w}, w4.w, acc);
            }
        }
        v2f a2 = vmax2(acc, (v2f){0.f, 0.f});

        float w20 = fw2[k], w21 = fw2[64 + k];
        v2f pz0 = a2 * (v2f){w20, w20};
        v2f pz1 = a2 * (v2f){w21, w21};
        #pragma unroll
        for (int off = 32; off > 0; off >>= 1) {
            pz0.x += __shfl_xor(pz0.x, off, 64);
            pz0.y += __shfl_xor(pz0.y, off, 64);
            pz1.x += __shfl_xor(pz1.x, off, 64);
            pz1.y += __shfl_xor(pz1.y, off, 64);
        }
        int h = (t >> 5) & 1;                 // half-wave -> sample within pair
        float x0 = (h ? pz0.y : pz0.x) + fb2[0];
        float x1 = (h ? pz1.y : pz1.x) + fb2[1];

        // 2-qubit circuit
        float sr[4], si[4];
        {
            float th0 = -x0 - x1, th1 = -x0 + x1, th2 = x0 - x1, th3 = x0 + x1;
            sr[0] = 0.5f * __cosf(th0); si[0] = 0.5f * __sinf(th0);
            sr[1] = 0.5f * __cosf(th1); si[1] = 0.5f * __sinf(th1);
            sr[2] = 0.5f * __cosf(th2); si[2] = 0.5f * __sinf(th2);
            sr[3] = 0.5f * __cosf(th3); si[3] = 0.5f * __sinf(th3);
        }
        {
            float tr = sr[2]; sr[2] = sr[3]; sr[3] = tr;
            float ti = si[2]; si[2] = si[3]; si[3] = ti;
            float ang = ((float)M_PI - x0) * ((float)M_PI - x1);
            float ca = __cosf(ang), sa = __sinf(ang);
            float r, im;
            r = sr[0]; im = si[0]; sr[0] = r*ca + im*sa; si[0] = im*ca - r*sa;
            r = sr[2]; im = si[2]; sr[2] = r*ca + im*sa; si[2] = im*ca - r*sa;
            r = sr[1]; im = si[1]; sr[1] = r*ca - im*sa; si[1] = im*ca + r*sa;
            r = sr[3]; im = si[3]; sr[3] = r*ca - im*sa; si[3] = im*ca + r*sa;
            tr = sr[2]; sr[2] = sr[3]; sr[3] = tr;
            ti = si[2]; si[2] = si[3]; si[3] = ti;
        }
        float cp[8], sp[8];
        #pragma unroll
        for (int g = 0; g < 8; ++g) { float q = qp[g]; cp[g] = __cosf(q); sp[g] = __sinf(q); }

        #define QRY0(cc, ss) { \
            float a0r=sr[0], a0i=si[0], a1r=sr[2], a1i=si[2]; \
            sr[0]=cc*a0r-ss*a1r; si[0]=cc*a0i-ss*a1i; \
            sr[2]=ss*a0r+cc*a1r; si[2]=ss*a0i+cc*a1i; \
            float b0r=sr[1], b0i=si[1], b1r=sr[3], b1i=si[3]; \
            sr[1]=cc*b0r-ss*b1r; si[1]=cc*b0i-ss*b1i; \
            sr[3]=ss*b0r+cc*b1r; si[3]=ss*b0i+cc*b1i; }
        #define QRY1(cc, ss) { \
            float a0r=sr[0], a0i=si[0], a1r=sr[1], a1i=si[1]; \
            sr[0]=cc*a0r-ss*a1r; si[0]=cc*a0i-ss*a1i; \
            sr[1]=ss*a0r+cc*a1r; si[1]=ss*a0i+cc*a1i; \
            float b0r=sr[2], b0i=si[2], b1r=sr[3], b1i=si[3]; \
            sr[2]=cc*b0r-ss*b1r; si[2]=cc*b0i-ss*b1i; \
            sr[3]=ss*b0r+cc*b1r; si[3]=ss*b0i+cc*b1i; }
        #define QSWAP(i_, j_) { float tr=sr[i_]; sr[i_]=sr[j_]; sr[j_]=tr; \
                                float ti=si[i_]; si[i_]=si[j_]; si[j_]=ti; }

        QRY0(cp[0], sp[0]);
        QRY1(cp[1], sp[1]);
        QSWAP(2, 3);                 // cnot01
        QRY0(cp[2], sp[2]);
        QRY1(cp[3], sp[3]);
        QSWAP(1, 3);                 // cnot10
        QRY0(cp[4], sp[4]);
        QRY1(cp[5], sp[5]);
        QSWAP(2, 3);                 // cnot01
        QRY0(cp[6], sp[6]);
        QRY1(cp[7], sp[7]);

        float qv = (sr[0]*sr[0] + si[0]*si[0])
                 - (sr[1]*sr[1] + si[1]*si[1])
                 - (sr[2]*sr[2] + si[2]*si[2])
                 + (sr[3]*sr[3] + si[3]*si[3]);
        float y = fmaf(qv, fw3[0], fb3[0]);
        float l0 = y, l1 = 1.0f - y;
        float m = fmaxf(l0, l1);
        float lse = m + __logf(__expf(l0 - m) + __expf(l1 - m));
        int lk = t & 31;
        if (lk < 2) {
            float o = (lk == 0) ? (l0 - lse) : (l1 - lse);
            out[(base + 2 * p + h) * 2 + lk] = o;
        }
        #undef QRY0
        #undef QRY1
        #undef QSWAP
    }
}

extern "C" void kernel_launch(void* const* d_in, const int* in_sizes, int n_in,
                              void* d_out, int out_size, void* d_ws, size_t ws_size,
                              hipStream_t stream) {
    const float* x   = (const float*)d_in[0];
    const float* w1  = (const float*)d_in[1];
    const float* b1  = (const float*)d_in[2];
    const float* w2  = (const float*)d_in[3];
    const float* b2  = (const float*)d_in[4];
    const float* fw1 = (const float*)d_in[5];
    const float* fb1 = (const float*)d_in[6];
    const float* fw2 = (const float*)d_in[7];
    const float* fb2 = (const float*)d_in[8];
    const float* fw3 = (const float*)d_in[9];
    const float* fb3 = (const float*)d_in[10];
    const float* qp  = (const float*)d_in[11];
    float* outp = (float*)d_out;

    int B = in_sizes[0] / 784;     // 65536
    int nblk = B / 8;              // 8 samples (4 pairs) per block
    hipLaunchKernelGGL(hqcnn_fused, dim3(nblk), dim3(256), 0, stream,
                       x, w1, b1, w2, b2, fw1, fb1, fw2, fb2, fw3, fb3, qp, outp);
}

// Round 4
// 450.846 us; speedup vs baseline: 1.2698x; 1.2698x over previous
//
#include <hip/hip_runtime.h>
#include <math.h>

// Fused HQCNN, round 4: packed-fp32 pairs + wave-owns-pair structure.
// Block = 8 samples = 4 pairs, 256 threads; wave w owns pair w for conv1/conv2/tail.
// conv1 reads x directly from global (no xs staging); p1/hb pair-interleaved LDS;
// conv1->conv2 sync is wave-local s_waitcnt; only 3 light barriers total.
// fc1 weight-shared (fw1 read once per block), partials aliased onto dead p1.

typedef float v2f __attribute__((ext_vector_type(2)));
typedef float v4f __attribute__((ext_vector_type(4)));

static __device__ __forceinline__ v2f vfma2(v2f a, float w, v2f c) {
    return __builtin_elementwise_fma(a, (v2f){w, w}, c);
}
static __device__ __forceinline__ v2f vmax2(v2f a, v2f b) {
    return __builtin_elementwise_max(a, b);
}

#define P1_PAIR 580    // floats per pair (288*2 + 4 pad), v4f-aligned
#define HB_OC   36     // floats per oc (16*2 + 4 pad)
#define HB_PAIR 576    // 16 * HB_OC
#define W2_OC   60     // padded conv2 weights per oc

__global__ __launch_bounds__(256, 5)
void hqcnn_fused(const float* __restrict__ x,    // (B,1,28,28)
                 const float* __restrict__ w1,   // (2,1,5,5)
                 const float* __restrict__ b1,   // (2,)
                 const float* __restrict__ w2,   // (16,2,5,5)
                 const float* __restrict__ b2,   // (16,)
                 const float* __restrict__ fw1,  // (64,256)
                 const float* __restrict__ fb1,  // (64,)
                 const float* __restrict__ fw2,  // (2,64)
                 const float* __restrict__ fb2,  // (2,)
                 const float* __restrict__ fw3,  // (1,1)
                 const float* __restrict__ fb3,  // (1,)
                 const float* __restrict__ qp,   // (8,)
                 float* __restrict__ out)        // (B,2)
{
    __shared__ __align__(16) float p1s[4 * P1_PAIR];   // 9280 B; aliased as pbuf in fc1
    __shared__ __align__(16) float hb[4 * HB_PAIR];    // 9216 B
    __shared__ __align__(16) float w2s[16 * W2_OC];    // 3840 B

    const int t = threadIdx.x;
    const int wv = t >> 6;          // wave == pair
    const int lane = t & 63;
    const long base = (long)blockIdx.x * 8;

    // ---- stage conv2 weights (padded) ----
    for (int f = t; f < 800; f += 256) {
        int oc = f / 50;
        int rem = f - oc * 50;
        int c = rem >= 25;
        int k = rem - c * 25;
        w2s[oc * W2_OC + c * 28 + k] = w2[f];
    }
    __syncthreads();

    // ---- conv1 + relu + pool (wave-local, x from global, packed pairs) ----
    {
        float w1c[50];
        #pragma unroll
        for (int i = 0; i < 50; ++i) w1c[i] = w1[i];    // wave-uniform -> s_load
        const float bb0 = b1[0], bb1 = b1[1];
        const float* xA = x + (base + 2 * wv) * 784;
        const float* xB = xA + 784;

        for (int f = lane; f < 72; f += 64) {
            int i = f / 6, jh = f - i * 6;
            v2f acc[16];                                 // [c][a][b]
            #pragma unroll
            for (int q = 0; q < 16; ++q) acc[q] = (v2f){0.f, 0.f};
            #pragma unroll
            for (int u = 0; u < 6; ++u) {
                const v4f* pA = (const v4f*)(xA + (2 * i + u) * 28 + 4 * jh);
                const v4f* pB = (const v4f*)(xB + (2 * i + u) * 28 + 4 * jh);
                v4f a0 = pA[0], a1 = pA[1];
                v4f b0 = pB[0], b1v = pB[1];
                v2f rr[8] = { {a0.x,b0.x},{a0.y,b0.y},{a0.z,b0.z},{a0.w,b0.w},
                              {a1.x,b1v.x},{a1.y,b1v.y},{a1.z,b1v.z},{a1.w,b1v.w} };
                #pragma unroll
                for (int a = 0; a < 2; ++a) {
                    if (a <= u && (u - a) <= 4) {
                        const int wu = u - a;
                        #pragma unroll
                        for (int c = 0; c < 2; ++c)
                            #pragma unroll
                            for (int b = 0; b < 4; ++b) {
                                v2f s0 = acc[c * 8 + a * 4 + b];
                                #pragma unroll
                                for (int v = 0; v < 5; ++v)
                                    s0 = vfma2(rr[b + v], w1c[c * 25 + wu * 5 + v], s0);
                                acc[c * 8 + a * 4 + b] = s0;
                            }
                    }
                }
            }
            #pragma unroll
            for (int c = 0; c < 2; ++c) {
                float bias = c ? bb1 : bb0;
                #pragma unroll
                for (int bb = 0; bb < 2; ++bb) {
                    v2f m = vmax2(vmax2(acc[c*8 + 2*bb],     acc[c*8 + 2*bb + 1]),
                                  vmax2(acc[c*8 + 4 + 2*bb], acc[c*8 + 4 + 2*bb + 1]));
                    m = m + (v2f){bias, bias};
                    m = vmax2(m, (v2f){0.f, 0.f});
                    ((v2f*)p1s)[wv * (P1_PAIR / 2) + c * 144 + i * 12 + 2 * jh + bb] = m;
                }
            }
        }
    }
    // wave-local producer->consumer fence (no block barrier needed)
    asm volatile("s_waitcnt lgkmcnt(0)" ::: "memory");

    // ---- conv2 + relu + pool (wave-local, packed) ----
    {
        int oc = (lane >> 2) & 15;
        int qi = (lane >> 1) & 1;
        int qj = lane & 1;
        v2f acc[16];                                    // [a][b]
        #pragma unroll
        for (int q = 0; q < 16; ++q) acc[q] = (v2f){0.f, 0.f};
        #pragma unroll
        for (int c = 0; c < 2; ++c) {
            float wvv[28];
            {
                const v4f* wp = (const v4f*)w2s + oc * (W2_OC / 4) + c * 7;
                #pragma unroll
                for (int j = 0; j < 7; ++j) {
                    v4f w4 = wp[j];
                    wvv[j*4+0] = w4.x; wvv[j*4+1] = w4.y; wvv[j*4+2] = w4.z; wvv[j*4+3] = w4.w;
                }
            }
            #pragma unroll
            for (int u = 0; u < 8; ++u) {
                int rb = wv * (P1_PAIR / 4) + c * 72 + (4 * qi + u) * 6 + 2 * qj;
                v4f q0 = ((const v4f*)p1s)[rb + 0];
                v4f q1 = ((const v4f*)p1s)[rb + 1];
                v4f q2 = ((const v4f*)p1s)[rb + 2];
                v4f q3 = ((const v4f*)p1s)[rb + 3];
                v2f rr[8] = { {q0.x,q0.y},{q0.z,q0.w},{q1.x,q1.y},{q1.z,q1.w},
                              {q2.x,q2.y},{q2.z,q2.w},{q3.x,q3.y},{q3.z,q3.w} };
                #pragma unroll
                for (int a = 0; a < 4; ++a) {
                    if (a <= u && (u - a) <= 4) {
                        const int wu = u - a;
                        #pragma unroll
                        for (int b = 0; b < 4; ++b) {
                            v2f s0 = acc[a * 4 + b];
                            #pragma unroll
                            for (int v = 0; v < 5; ++v)
                                s0 = vfma2(rr[b + v], wvv[wu * 5 + v], s0);
                            acc[a * 4 + b] = s0;
                        }
                    }
                }
            }
        }
        float bias = b2[oc];
        #pragma unroll
        for (int a2 = 0; a2 < 2; ++a2)
            #pragma unroll
            for (int b2i = 0; b2i < 2; ++b2i) {
                v2f m = vmax2(vmax2(acc[(2*a2)*4 + 2*b2i],     acc[(2*a2)*4 + 2*b2i + 1]),
                              vmax2(acc[(2*a2+1)*4 + 2*b2i], acc[(2*a2+1)*4 + 2*b2i + 1]));
                m = m + (v2f){bias, bias};
                m = vmax2(m, (v2f){0.f, 0.f});
                int pos = (2*qi + a2) * 4 + (2*qj + b2i);
                ((v2f*)hb)[wv * (HB_PAIR / 2) + oc * (HB_OC / 2) + pos] = m;
            }
    }
    __syncthreads();

    // ---- fc1 partials (weight-shared: fw1 read once per block) ----
    // thread (k=lane, chunk=wv): rows k, weight-cols [wv*64, wv*64+64), all 4 pairs.
    {
        const v4f* wrow = (const v4f*)(fw1 + lane * 256 + wv * 64);
        v2f part[4];
        #pragma unroll
        for (int p = 0; p < 4; ++p) part[p] = (v2f){0.f, 0.f};
        #pragma unroll
        for (int jo = 0; jo < 4; ++jo) {
            int oc = wv * 4 + jo;
            #pragma unroll
            for (int jj = 0; jj < 4; ++jj) {
                v4f w4 = wrow[jo * 4 + jj];
                #pragma unroll
                for (int p = 0; p < 4; ++p) {
                    const v4f* hp = (const v4f*)(hb + p * HB_PAIR + oc * HB_OC + jj * 8);
                    v4f hA = hp[0], hB = hp[1];      // wave-uniform -> LDS broadcast
                    part[p] = vfma2((v2f){hA.x, hA.y}, w4.x, part[p]);
                    part[p] = vfma2((v2f){hA.z, hA.w}, w4.y, part[p]);
                    part[p] = vfma2((v2f){hB.x, hB.y}, w4.z, part[p]);
                    part[p] = vfma2((v2f){hB.z, hB.w}, w4.w, part[p]);
                }
            }
        }
        v2f* pb = (v2f*)p1s;                           // p1 is dead -> alias as pbuf
        #pragma unroll
        for (int p = 0; p < 4; ++p)
            pb[(wv * 4 + p) * 64 + lane] = part[p];
    }
    __syncthreads();

    // ---- fc1 reduce + fc2 (wave reduce) + quantum + fc3 + log_softmax ----
    {
        const v2f* pb = (const v2f*)p1s;
        float fb = fb1[lane];
        v2f acc = (v2f){fb, fb};
        acc = acc + pb[(0 * 4 + wv) * 64 + lane];
        acc = acc + pb[(1 * 4 + wv) * 64 + lane];
        acc = acc + pb[(2 * 4 + wv) * 64 + lane];
        acc = acc + pb[(3 * 4 + wv) * 64 + lane];
        v2f a2 = vmax2(acc, (v2f){0.f, 0.f});

        float w20 = fw2[lane], w21 = fw2[64 + lane];
        v2f pz0 = a2 * (v2f){w20, w20};
        v2f pz1 = a2 * (v2f){w21, w21};
        #pragma unroll
        for (int off = 32; off > 0; off >>= 1) {
            pz0.x += __shfl_xor(pz0.x, off, 64);
            pz0.y += __shfl_xor(pz0.y, off, 64);
            pz1.x += __shfl_xor(pz1.x, off, 64);
            pz1.y += __shfl_xor(pz1.y, off, 64);
        }
        int h = lane >> 5;                 // half-wave -> sample within pair
        float x0 = (h ? pz0.y : pz0.x) + fb2[0];
        float x1 = (h ? pz1.y : pz1.x) + fb2[1];

        // 2-qubit circuit (all lanes redundantly)
        float sr[4], si[4];
        {
            float th0 = -x0 - x1, th1 = -x0 + x1, th2 = x0 - x1, th3 = x0 + x1;
            sr[0] = 0.5f * __cosf(th0); si[0] = 0.5f * __sinf(th0);
            sr[1] = 0.5f * __cosf(th1); si[1] = 0.5f * __sinf(th1);
            sr[2] = 0.5f * __cosf(th2); si[2] = 0.5f * __sinf(th2);
            sr[3] = 0.5f * __cosf(th3); si[3] = 0.5f * __sinf(th3);
        }
        {
            float tr = sr[2]; sr[2] = sr[3]; sr[3] = tr;
            float ti = si[2]; si[2] = si[3]; si[3] = ti;
            float ang = ((float)M_PI - x0) * ((float)M_PI - x1);
            float ca = __cosf(ang), sa = __sinf(ang);
            float r, im;
            r = sr[0]; im = si[0]; sr[0] = r*ca + im*sa; si[0] = im*ca - r*sa;
            r = sr[2]; im = si[2]; sr[2] = r*ca + im*sa; si[2] = im*ca - r*sa;
            r = sr[1]; im = si[1]; sr[1] = r*ca - im*sa; si[1] = im*ca + r*sa;
            r = sr[3]; im = si[3]; sr[3] = r*ca - im*sa; si[3] = im*ca + r*sa;
            tr = sr[2]; sr[2] = sr[3]; sr[3] = tr;
            ti = si[2]; si[2] = si[3]; si[3] = ti;
        }
        float cp[8], sp[8];
        #pragma unroll
        for (int g = 0; g < 8; ++g) { float q = qp[g]; cp[g] = __cosf(q); sp[g] = __sinf(q); }

        #define QRY0(cc, ss) { \
            float a0r=sr[0], a0i=si[0], a1r=sr[2], a1i=si[2]; \
            sr[0]=cc*a0r-ss*a1r; si[0]=cc*a0i-ss*a1i; \
            sr[2]=ss*a0r+cc*a1r; si[2]=ss*a0i+cc*a1i; \
            float b0r=sr[1], b0i=si[1], b1r=sr[3], b1i=si[3]; \
            sr[1]=cc*b0r-ss*b1r; si[1]=cc*b0i-ss*b1i; \
            sr[3]=ss*b0r+cc*b1r; si[3]=ss*b0i+cc*b1i; }
        #define QRY1(cc, ss) { \
            float a0r=sr[0], a0i=si[0], a1r=sr[1], a1i=si[1]; \
            sr[0]=cc*a0r-ss*a1r; si[0]=cc*a0i-ss*a1i; \
            sr[1]=ss*a0r+cc*a1r; si[1]=ss*a0i+cc*a1i; \
            float b0r=sr[2], b0i=si[2], b1r=sr[3], b1i=si[3]; \
            sr[2]=cc*b0r-ss*b1r; si[2]=cc*b0i-ss*b1i; \
            sr[3]=ss*b0r+cc*b1r; si[3]=ss*b0i+cc*b1i; }
        #define QSWAP(i_, j_) { float tr=sr[i_]; sr[i_]=sr[j_]; sr[j_]=tr; \
                                float ti=si[i_]; si[i_]=si[j_]; si[j_]=ti; }

        QRY0(cp[0], sp[0]);
        QRY1(cp[1], sp[1]);
        QSWAP(2, 3);                 // cnot01
        QRY0(cp[2], sp[2]);
        QRY1(cp[3], sp[3]);
        QSWAP(1, 3);                 // cnot10
        QRY0(cp[4], sp[4]);
        QRY1(cp[5], sp[5]);
        QSWAP(2, 3);                 // cnot01
        QRY0(cp[6], sp[6]);
        QRY1(cp[7], sp[7]);

        float qv = (sr[0]*sr[0] + si[0]*si[0])
                 - (sr[1]*sr[1] + si[1]*si[1])
                 - (sr[2]*sr[2] + si[2]*si[2])
                 + (sr[3]*sr[3] + si[3]*si[3]);
        float y = fmaf(qv, fw3[0], fb3[0]);
        float l0 = y, l1 = 1.0f - y;
        float m = fmaxf(l0, l1);
        float lse = m + __logf(__expf(l0 - m) + __expf(l1 - m));
        int lk = lane & 31;
        if (lk < 2) {
            float o = (lk == 0) ? (l0 - lse) : (l1 - lse);
            out[(base + 2 * wv + h) * 2 + lk] = o;
        }
        #undef QRY0
        #undef QRY1
        #undef QSWAP
    }
}

extern "C" void kernel_launch(void* const* d_in, const int* in_sizes, int n_in,
                              void* d_out, int out_size, void* d_ws, size_t ws_size,
                              hipStream_t stream) {
    const float* x   = (const float*)d_in[0];
    const float* w1  = (const float*)d_in[1];
    const float* b1  = (const float*)d_in[2];
    const float* w2  = (const float*)d_in[3];
    const float* b2  = (const float*)d_in[4];
    const float* fw1 = (const float*)d_in[5];
    const float* fb1 = (const float*)d_in[6];
    const float* fw2 = (const float*)d_in[7];
    const float* fb2 = (const float*)d_in[8];
    const float* fw3 = (const float*)d_in[9];
    const float* fb3 = (const float*)d_in[10];
    const float* qp  = (const float*)d_in[11];
    float* outp = (float*)d_out;

    int B = in_sizes[0] / 784;     // 65536
    int nblk = B / 8;              // 8 samples (4 pairs) per block
    hipLaunchKernelGGL(hqcnn_fused, dim3(nblk), dim3(256), 0, stream,
                       x, w1, b1, w2, b2, fw1, fb1, fw2, fb2, fw3, fb3, qp, outp);
}

// Round 5
// 413.606 us; speedup vs baseline: 1.3841x; 1.0900x over previous
//
#include <hip/hip_runtime.h>
#include <math.h>

// Fused HQCNN, round 5.
// conv1: channel-packed pk_fma with op_sel splat (inline asm) — no zip movs,
//        weights in SGPR pairs, 96 jobs = 2 samples x 12 rows x 4 col-groups.
// conv2/fc1/fc2/tail: unchanged from round 4 (sample-pair packed).

typedef float v2f __attribute__((ext_vector_type(2)));
typedef float v4f __attribute__((ext_vector_type(4)));

static __device__ __forceinline__ v2f vfma2(v2f a, float w, v2f c) {
    return __builtin_elementwise_fma(a, (v2f){w, w}, c);
}
static __device__ __forceinline__ v2f vmax2(v2f a, v2f b) {
    return __builtin_elementwise_max(a, b);
}

// acc = w * splat(x.word) + acc ; w is wave-uniform (SGPR pair), x is v2f.
#define PK_FMA_W0(acc, w, xp) \
    asm("v_pk_fma_f32 %0, %1, %2, %0 op_sel:[0,0,0] op_sel_hi:[1,0,1]" \
        : "+v"(acc) : "s"(w), "v"(xp))
#define PK_FMA_W1(acc, w, xp) \
    asm("v_pk_fma_f32 %0, %1, %2, %0 op_sel:[0,1,0] op_sel_hi:[1,1,1]" \
        : "+v"(acc) : "s"(w), "v"(xp))

#define P1_PAIR 580    // floats per pair (288*2 + 4 pad), v4f-aligned
#define HB_OC   36     // floats per oc (16*2 + 4 pad)
#define HB_PAIR 576    // 16 * HB_OC
#define W2_OC   60     // padded conv2 weights per oc

__global__ __launch_bounds__(256, 5)
void hqcnn_fused(const float* __restrict__ x,    // (B,1,28,28)
                 const float* __restrict__ w1,   // (2,1,5,5)
                 const float* __restrict__ b1,   // (2,)
                 const float* __restrict__ w2,   // (16,2,5,5)
                 const float* __restrict__ b2,   // (16,)
                 const float* __restrict__ fw1,  // (64,256)
                 const float* __restrict__ fb1,  // (64,)
                 const float* __restrict__ fw2,  // (2,64)
                 const float* __restrict__ fb2,  // (2,)
                 const float* __restrict__ fw3,  // (1,1)
                 const float* __restrict__ fb3,  // (1,)
                 const float* __restrict__ qp,   // (8,)
                 float* __restrict__ out)        // (B,2)
{
    __shared__ __align__(16) float p1s[4 * P1_PAIR];   // 9280 B; aliased as pbuf in fc1
    __shared__ __align__(16) float hb[4 * HB_PAIR];    // 9216 B
    __shared__ __align__(16) float w2s[16 * W2_OC];    // 3840 B

    const int t = threadIdx.x;
    const int wv = t >> 6;          // wave == pair
    const int lane = t & 63;
    const long base = (long)blockIdx.x * 8;

    // ---- stage conv2 weights (padded) ----
    for (int f = t; f < 800; f += 256) {
        int oc = f / 50;
        int rem = f - oc * 50;
        int c = rem >= 25;
        int k = rem - c * 25;
        w2s[oc * W2_OC + c * 28 + k] = w2[f];
    }
    __syncthreads();

    // ---- conv1 + relu + pool: channel-packed, op_sel splat, x from global ----
    // 96 jobs/wave: (s in pair, i = pooled row, jh = 3-pooled-col group)
    {
        v2f w1p[25];
        #pragma unroll
        for (int k = 0; k < 25; ++k)
            w1p[k] = (v2f){w1[k], w1[25 + k]};          // wave-uniform -> SGPR pairs
        const v2f bias1 = (v2f){b1[0], b1[1]};

        #pragma unroll
        for (int it = 0; it < 2; ++it) {
            int f = lane + it * 64;
            if (f < 96) {
                int s = f / 48;
                int r = f - s * 48;
                int i = r >> 2, jh = r & 3;
                const float* xrow = x + (base + 2 * wv + s) * 784;
                v2f acc[12];                             // [a][j], a=conv row, j=conv col
                #pragma unroll
                for (int q = 0; q < 12; ++q) acc[q] = (v2f){0.f, 0.f};
                #pragma unroll
                for (int u = 0; u < 6; ++u) {
                    const v2f* xp = (const v2f*)(xrow + (2 * i + u) * 28 + 6 * jh);
                    v2f P[5] = { xp[0], xp[1], xp[2], xp[3], xp[4] };
                    #pragma unroll
                    for (int a = 0; a < 2; ++a) {
                        if (a <= u && (u - a) <= 4) {
                            const int wu = u - a;
                            #pragma unroll
                            for (int v = 0; v < 5; ++v) {
                                #pragma unroll
                                for (int j = 0; j < 6; ++j) {
                                    const int e = j + v;
                                    if (e & 1) { PK_FMA_W1(acc[a * 6 + j], w1p[wu * 5 + v], P[e >> 1]); }
                                    else       { PK_FMA_W0(acc[a * 6 + j], w1p[wu * 5 + v], P[e >> 1]); }
                                }
                            }
                        }
                    }
                }
                // pool 2x2 + bias + relu, scatter into pair-interleaved p1
                #pragma unroll
                for (int m = 0; m < 3; ++m) {
                    v2f mx = vmax2(vmax2(acc[2 * m], acc[2 * m + 1]),
                                   vmax2(acc[6 + 2 * m], acc[7 + 2 * m]));
                    mx = mx + bias1;
                    mx = vmax2(mx, (v2f){0.f, 0.f});
                    int pc = 3 * jh + m;
                    int off = wv * P1_PAIR + 2 * (i * 12 + pc) + s;
                    p1s[off] = mx.x;              // channel 0 plane
                    p1s[off + 288] = mx.y;        // channel 1 plane (2*144)
                }
            }
        }
    }
    // wave-local producer->consumer fence (no block barrier needed)
    asm volatile("s_waitcnt lgkmcnt(0)" ::: "memory");

    // ---- conv2 + relu + pool (wave-local, sample-pair packed) ----
    {
        int oc = (lane >> 2) & 15;
        int qi = (lane >> 1) & 1;
        int qj = lane & 1;
        v2f acc[16];                                    // [a][b]
        #pragma unroll
        for (int q = 0; q < 16; ++q) acc[q] = (v2f){0.f, 0.f};
        #pragma unroll
        for (int c = 0; c < 2; ++c) {
            float wvv[28];
            {
                const v4f* wp = (const v4f*)w2s + oc * (W2_OC / 4) + c * 7;
                #pragma unroll
                for (int j = 0; j < 7; ++j) {
                    v4f w4 = wp[j];
                    wvv[j*4+0] = w4.x; wvv[j*4+1] = w4.y; wvv[j*4+2] = w4.z; wvv[j*4+3] = w4.w;
                }
            }
            #pragma unroll
            for (int u = 0; u < 8; ++u) {
                int rb = wv * (P1_PAIR / 4) + c * 72 + (4 * qi + u) * 6 + 2 * qj;
                v4f q0 = ((const v4f*)p1s)[rb + 0];
                v4f q1 = ((const v4f*)p1s)[rb + 1];
                v4f q2 = ((const v4f*)p1s)[rb + 2];
                v4f q3 = ((const v4f*)p1s)[rb + 3];
                v2f rr[8] = { {q0.x,q0.y},{q0.z,q0.w},{q1.x,q1.y},{q1.z,q1.w},
                              {q2.x,q2.y},{q2.z,q2.w},{q3.x,q3.y},{q3.z,q3.w} };
                #pragma unroll
                for (int a = 0; a < 4; ++a) {
                    if (a <= u && (u - a) <= 4) {
                        const int wu = u - a;
                        #pragma unroll
                        for (int b = 0; b < 4; ++b) {
                            v2f s0 = acc[a * 4 + b];
                            #pragma unroll
                            for (int v = 0; v < 5; ++v)
                                s0 = vfma2(rr[b + v], wvv[wu * 5 + v], s0);
                            acc[a * 4 + b] = s0;
                        }
                    }
                }
            }
        }
        float bias = b2[oc];
        #pragma unroll
        for (int a2 = 0; a2 < 2; ++a2)
            #pragma unroll
            for (int b2i = 0; b2i < 2; ++b2i) {
                v2f m = vmax2(vmax2(acc[(2*a2)*4 + 2*b2i],     acc[(2*a2)*4 + 2*b2i + 1]),
                              vmax2(acc[(2*a2+1)*4 + 2*b2i], acc[(2*a2+1)*4 + 2*b2i + 1]));
                m = m + (v2f){bias, bias};
                m = vmax2(m, (v2f){0.f, 0.f});
                int pos = (2*qi + a2) * 4 + (2*qj + b2i);
                ((v2f*)hb)[wv * (HB_PAIR / 2) + oc * (HB_OC / 2) + pos] = m;
            }
    }
    __syncthreads();

    // ---- fc1 partials (weight-shared: fw1 read once per block) ----
    {
        const v4f* wrow = (const v4f*)(fw1 + lane * 256 + wv * 64);
        v2f part[4];
        #pragma unroll
        for (int p = 0; p < 4; ++p) part[p] = (v2f){0.f, 0.f};
        #pragma unroll
        for (int jo = 0; jo < 4; ++jo) {
            int oc = wv * 4 + jo;
            #pragma unroll
            for (int jj = 0; jj < 4; ++jj) {
                v4f w4 = wrow[jo * 4 + jj];
                #pragma unroll
                for (int p = 0; p < 4; ++p) {
                    const v4f* hp = (const v4f*)(hb + p * HB_PAIR + oc * HB_OC + jj * 8);
                    v4f hA = hp[0], hB = hp[1];      // wave-uniform -> LDS broadcast
                    part[p] = vfma2((v2f){hA.x, hA.y}, w4.x, part[p]);
                    part[p] = vfma2((v2f){hA.z, hA.w}, w4.y, part[p]);
                    part[p] = vfma2((v2f){hB.x, hB.y}, w4.z, part[p]);
                    part[p] = vfma2((v2f){hB.z, hB.w}, w4.w, part[p]);
                }
            }
        }
        v2f* pb = (v2f*)p1s;                           // p1 is dead -> alias as pbuf
        #pragma unroll
        for (int p = 0; p < 4; ++p)
            pb[(wv * 4 + p) * 64 + lane] = part[p];
    }
    __syncthreads();

    // ---- fc1 reduce + fc2 (wave reduce) + quantum + fc3 + log_softmax ----
    {
        const v2f* pb = (const v2f*)p1s;
        float fb = fb1[lane];
        v2f acc = (v2f){fb, fb};
        acc = acc + pb[(0 * 4 + wv) * 64 + lane];
        acc = acc + pb[(1 * 4 + wv) * 64 + lane];
        acc = acc + pb[(2 * 4 + wv) * 64 + lane];
        acc = acc + pb[(3 * 4 + wv) * 64 + lane];
        v2f a2 = vmax2(acc, (v2f){0.f, 0.f});

        float w20 = fw2[lane], w21 = fw2[64 + lane];
        v2f pz0 = a2 * (v2f){w20, w20};
        v2f pz1 = a2 * (v2f){w21, w21};
        #pragma unroll
        for (int off = 32; off > 0; off >>= 1) {
            pz0.x += __shfl_xor(pz0.x, off, 64);
            pz0.y += __shfl_xor(pz0.y, off, 64);
            pz1.x += __shfl_xor(pz1.x, off, 64);
            pz1.y += __shfl_xor(pz1.y, off, 64);
        }
        int h = lane >> 5;                 // half-wave -> sample within pair
        float x0 = (h ? pz0.y : pz0.x) + fb2[0];
        float x1 = (h ? pz1.y : pz1.x) + fb2[1];

        // 2-qubit circuit (all lanes redundantly)
        float sr[4], si[4];
        {
            float th0 = -x0 - x1, th1 = -x0 + x1, th2 = x0 - x1, th3 = x0 + x1;
            sr[0] = 0.5f * __cosf(th0); si[0] = 0.5f * __sinf(th0);
            sr[1] = 0.5f * __cosf(th1); si[1] = 0.5f * __sinf(th1);
            sr[2] = 0.5f * __cosf(th2); si[2] = 0.5f * __sinf(th2);
            sr[3] = 0.5f * __cosf(th3); si[3] = 0.5f * __sinf(th3);
        }
        {
            float tr = sr[2]; sr[2] = sr[3]; sr[3] = tr;
            float ti = si[2]; si[2] = si[3]; si[3] = ti;
            float ang = ((float)M_PI - x0) * ((float)M_PI - x1);
            float ca = __cosf(ang), sa = __sinf(ang);
            float r, im;
            r = sr[0]; im = si[0]; sr[0] = r*ca + im*sa; si[0] = im*ca - r*sa;
            r = sr[2]; im = si[2]; sr[2] = r*ca + im*sa; si[2] = im*ca - r*sa;
            r = sr[1]; im = si[1]; sr[1] = r*ca - im*sa; si[1] = im*ca + r*sa;
            r = sr[3]; im = si[3]; sr[3] = r*ca - im*sa; si[3] = im*ca + r*sa;
            tr = sr[2]; sr[2] = sr[3]; sr[3] = tr;
            ti = si[2]; si[2] = si[3]; si[3] = ti;
        }
        float cp[8], sp[8];
        #pragma unroll
        for (int g = 0; g < 8; ++g) { float q = qp[g]; cp[g] = __cosf(q); sp[g] = __sinf(q); }

        #define QRY0(cc, ss) { \
            float a0r=sr[0], a0i=si[0], a1r=sr[2], a1i=si[2]; \
            sr[0]=cc*a0r-ss*a1r; si[0]=cc*a0i-ss*a1i; \
            sr[2]=ss*a0r+cc*a1r; si[2]=ss*a0i+cc*a1i; \
            float b0r=sr[1], b0i=si[1], b1r=sr[3], b1i=si[3]; \
            sr[1]=cc*b0r-ss*b1r; si[1]=cc*b0i-ss*b1i; \
            sr[3]=ss*b0r+cc*b1r; si[3]=ss*b0i+cc*b1i; }
        #define QRY1(cc, ss) { \
            float a0r=sr[0], a0i=si[0], a1r=sr[1], a1i=si[1]; \
            sr[0]=cc*a0r-ss*a1r; si[0]=cc*a0i-ss*a1i; \
            sr[1]=ss*a0r+cc*a1r; si[1]=ss*a0i+cc*a1i; \
            float b0r=sr[2], b0i=si[2], b1r=sr[3], b1i=si[3]; \
            sr[2]=cc*b0r-ss*b1r; si[2]=cc*b0i-ss*b1i; \
            sr[3]=ss*b0r+cc*b1r; si[3]=ss*b0i+cc*b1i; }
        #define QSWAP(i_, j_) { float tr=sr[i_]; sr[i_]=sr[j_]; sr[j_]=tr; \
                                float ti=si[i_]; si[i_]=si[j_]; si[j_]=ti; }

        QRY0(cp[0], sp[0]);
        QRY1(cp[1], sp[1]);
        QSWAP(2, 3);                 // cnot01
        QRY0(cp[2], sp[2]);
        QRY1(cp[3], sp[3]);
        QSWAP(1, 3);                 // cnot10
        QRY0(cp[4], sp[4]);
        QRY1(cp[5], sp[5]);
        QSWAP(2, 3);                 // cnot01
        QRY0(cp[6], sp[6]);
        QRY1(cp[7], sp[7]);

        float qv = (sr[0]*sr[0] + si[0]*si[0])
                 - (sr[1]*sr[1] + si[1]*si[1])
                 - (sr[2]*sr[2] + si[2]*si[2])
                 + (sr[3]*sr[3] + si[3]*si[3]);
        float y = fmaf(qv, fw3[0], fb3[0]);
        float l0 = y, l1 = 1.0f - y;
        float m = fmaxf(l0, l1);
        float lse = m + __logf(__expf(l0 - m) + __expf(l1 - m));
        int lk = lane & 31;
        if (lk < 2) {
            float o = (lk == 0) ? (l0 - lse) : (l1 - lse);
            out[(base + 2 * wv + h) * 2 + lk] = o;
        }
        #undef QRY0
        #undef QRY1
        #undef QSWAP
    }
}

extern "C" void kernel_launch(void* const* d_in, const int* in_sizes, int n_in,
                              void* d_out, int out_size, void* d_ws, size_t ws_size,
                              hipStream_t stream) {
    const float* x   = (const float*)d_in[0];
    const float* w1  = (const float*)d_in[1];
    const float* b1  = (const float*)d_in[2];
    const float* w2  = (const float*)d_in[3];
    const float* b2  = (const float*)d_in[4];
    const float* fw1 = (const float*)d_in[5];
    const float* fb1 = (const float*)d_in[6];
    const float* fw2 = (const float*)d_in[7];
    const float* fb2 = (const float*)d_in[8];
    const float* fw3 = (const float*)d_in[9];
    const float* fb3 = (const float*)d_in[10];
    const float* qp  = (const float*)d_in[11];
    float* outp = (float*)d_out;

    int B = in_sizes[0] / 784;     // 65536
    int nblk = B / 8;              // 8 samples (4 pairs) per block
    hipLaunchKernelGGL(hqcnn_fused, dim3(nblk), dim3(256), 0, stream,
                       x, w1, b1, w2, b2, fw1, fb1, fw2, fb2, fw3, fb3, qp, outp);
}

// Round 6
// 398.964 us; speedup vs baseline: 1.4349x; 1.0367x over previous
//
#include <hip/hip_runtime.h>
#include <math.h>

// Fused HQCNN, round 6: split-bf16 (hi+lo) MFMA for conv2 + fc1.
// Block = 8 samples = 4 pairs, 256 threads; wave wv owns pair wv for conv1/conv2.
// conv1: fp32 channel-packed pk_fma (round-5 code), output planar per-sample.
// conv2: per-sample GEMM on mfma_f32_16x16x32_bf16, 3-MFMA split (hihi+hilo+lohi),
//        B-frag gathered from p1 LDS, pooling via shfl_xor on D-frags.
// fc1:   GEMM M=64,K=256,N=8 on MFMA, A-frags pre-split into d_ws by prologue.
// fc2/quantum/log_softmax: wave partials + LDS reduce + redundant tail.

typedef float v2f __attribute__((ext_vector_type(2)));
typedef float f32x4 __attribute__((ext_vector_type(4)));
typedef short bf16x8 __attribute__((ext_vector_type(8)));

union B8 { unsigned int u[4]; bf16x8 v; };

static __device__ __forceinline__ v2f vfma2(v2f a, float w, v2f c) {
    return __builtin_elementwise_fma(a, (v2f){w, w}, c);
}
static __device__ __forceinline__ v2f vmax2(v2f a, v2f b) {
    return __builtin_elementwise_max(a, b);
}

// acc = w * splat(x.word) + acc ; w wave-uniform (SGPR pair), x v2f.
#define PK_FMA_W0(acc, w, xp) \
    asm("v_pk_fma_f32 %0, %1, %2, %0 op_sel:[0,0,0] op_sel_hi:[1,0,1]" \
        : "+v"(acc) : "s"(w), "v"(xp))
#define PK_FMA_W1(acc, w, xp) \
    asm("v_pk_fma_f32 %0, %1, %2, %0 op_sel:[0,1,0] op_sel_hi:[1,1,1]" \
        : "+v"(acc) : "s"(w), "v"(xp))

#define MFMA16(a, b, c) __builtin_amdgcn_mfma_f32_16x16x32_bf16(a, b, c, 0, 0, 0)

// hi = trunc-bf16(f), lo = bf16(f - float(hi)); packed pairwise into dwords.
static __device__ __forceinline__ void pack_hilo(const float* f, bf16x8& bh, bf16x8& bl) {
    B8 H, L;
    #pragma unroll
    for (int jp = 0; jp < 4; ++jp) {
        unsigned int u0 = __float_as_uint(f[2 * jp]);
        unsigned int u1 = __float_as_uint(f[2 * jp + 1]);
        H.u[jp] = (u1 & 0xFFFF0000u) | (u0 >> 16);
        float l0 = f[2 * jp]     - __uint_as_float(u0 & 0xFFFF0000u);
        float l1 = f[2 * jp + 1] - __uint_as_float(u1 & 0xFFFF0000u);
        L.u[jp] = (__float_as_uint(l1) & 0xFFFF0000u) | (__float_as_uint(l0) >> 16);
    }
    bh = H.v; bl = L.v;
}

// ws layout (ushort units)
#define A2_HI 0
#define A2_LO 1024
#define A1_HI 2048
#define A1_LO (2048 + 16384)
// total 34816 ushorts = 69632 B

#define P1_S 292   // floats per sample: 2*144 + 4 pad
#define HB_S 260   // floats per sample: 256 + 4 pad

__global__ __launch_bounds__(256)
void hqcnn_prep(const float* __restrict__ w2, const float* __restrict__ fw1,
                unsigned short* __restrict__ ws) {
    int t = blockIdx.x * 256 + threadIdx.x;
    if (blockIdx.x == 0) {
        for (int e = threadIdx.x; e < 1024; e += 256) {
            int m = e >> 6, k = e & 63;
            int c = k >> 5, uv = k & 31;
            float val = (uv < 25) ? w2[m * 50 + c * 25 + uv] : 0.f;
            unsigned int u = __float_as_uint(val);
            float lo = val - __uint_as_float(u & 0xFFFF0000u);
            ws[A2_HI + e] = (unsigned short)(u >> 16);
            ws[A2_LO + e] = (unsigned short)(__float_as_uint(lo) >> 16);
        }
    }
    for (int e = t; e < 16384; e += gridDim.x * 256) {
        float val = fw1[e];
        unsigned int u = __float_as_uint(val);
        float lo = val - __uint_as_float(u & 0xFFFF0000u);
        ws[A1_HI + e] = (unsigned short)(u >> 16);
        ws[A1_LO + e] = (unsigned short)(__float_as_uint(lo) >> 16);
    }
}

__global__ __launch_bounds__(256, 6)
void hqcnn_fused(const float* __restrict__ x,    // (B,1,28,28)
                 const float* __restrict__ w1,   // (2,1,5,5)
                 const float* __restrict__ b1,   // (2,)
                 const float* __restrict__ b2,   // (16,)
                 const float* __restrict__ fb1,  // (64,)
                 const float* __restrict__ fw2,  // (2,64)
                 const float* __restrict__ fb2,  // (2,)
                 const float* __restrict__ fw3,  // (1,1)
                 const float* __restrict__ fb3,  // (1,)
                 const float* __restrict__ qp,   // (8,)
                 const unsigned short* __restrict__ ws,
                 float* __restrict__ out)        // (B,2)
{
    __shared__ __align__(16) float p1s[8 * P1_S];   // 9344 B, per-sample planar
    __shared__ __align__(16) float hbs[8 * HB_S];   // 8320 B, per-sample planar
    __shared__ __align__(16) float zbuf[4 * 32];    //  512 B

    const int t = threadIdx.x;
    const int wv = t >> 6;
    const int lane = t & 63;
    const int n = lane & 15;
    const int q = lane >> 4;
    const long base = (long)blockIdx.x * 8;

    // ---- conv1 + relu + pool: fp32 ch-packed pk_fma, planar per-sample out ----
    {
        v2f w1p[25];
        #pragma unroll
        for (int k = 0; k < 25; ++k)
            w1p[k] = (v2f){w1[k], w1[25 + k]};          // wave-uniform -> SGPR pairs
        const v2f bias1 = (v2f){b1[0], b1[1]};

        #pragma unroll
        for (int it = 0; it < 2; ++it) {
            int f = lane + it * 64;
            if (f < 96) {
                int s = f / 48;
                int r = f - s * 48;
                int i = r >> 2, jh = r & 3;
                const float* xrow = x + (base + 2 * wv + s) * 784;
                v2f acc[12];
                #pragma unroll
                for (int qq = 0; qq < 12; ++qq) acc[qq] = (v2f){0.f, 0.f};
                #pragma unroll
                for (int u = 0; u < 6; ++u) {
                    const v2f* xp = (const v2f*)(xrow + (2 * i + u) * 28 + 6 * jh);
                    v2f P[5] = { xp[0], xp[1], xp[2], xp[3], xp[4] };
                    #pragma unroll
                    for (int a = 0; a < 2; ++a) {
                        if (a <= u && (u - a) <= 4) {
                            const int wu = u - a;
                            #pragma unroll
                            for (int v = 0; v < 5; ++v) {
                                #pragma unroll
                                for (int j = 0; j < 6; ++j) {
                                    const int e = j + v;
                                    if (e & 1) { PK_FMA_W1(acc[a * 6 + j], w1p[wu * 5 + v], P[e >> 1]); }
                                    else       { PK_FMA_W0(acc[a * 6 + j], w1p[wu * 5 + v], P[e >> 1]); }
                                }
                            }
                        }
                    }
                }
                #pragma unroll
                for (int m = 0; m < 3; ++m) {
                    v2f mx = vmax2(vmax2(acc[2 * m], acc[2 * m + 1]),
                                   vmax2(acc[6 + 2 * m], acc[7 + 2 * m]));
                    mx = mx + bias1;
                    mx = vmax2(mx, (v2f){0.f, 0.f});
                    int pc = 3 * jh + m;
                    int off = (2 * wv + s) * P1_S + i * 12 + pc;
                    p1s[off] = mx.x;            // channel 0 plane
                    p1s[off + 144] = mx.y;      // channel 1 plane
                }
            }
        }
    }
    // wave-local producer->consumer fence (conv2 reads only own pair's p1)
    asm volatile("s_waitcnt lgkmcnt(0)" ::: "memory");

    // ---- conv2 + relu + pool: split-bf16 MFMA GEMM per sample ----
    {
        // A-frags: A2[m=n][k=c*32+q*8+j], hi/lo, from prepped ws
        const bf16x8* A2h = (const bf16x8*)(ws + A2_HI);
        const bf16x8* A2l = (const bf16x8*)(ws + A2_LO);
        bf16x8 a_h0 = A2h[n * 8 + q],     a_h1 = A2h[n * 8 + 4 + q];
        bf16x8 a_l0 = A2l[n * 8 + q],     a_l1 = A2l[n * 8 + 4 + q];

        // per-lane gather offsets: k' = q*8+j -> uv -> (u,v) -> u*12+v
        int offs[8]; bool vld[8];
        #pragma unroll
        for (int j = 0; j < 8; ++j) {
            int uv = q * 8 + j;
            int u = (uv * 205) >> 10;      // uv/5 for uv<32
            int v = uv - u * 5;
            bool ok = uv < 25;
            offs[j] = ok ? (u * 12 + v) : 0;
            vld[j] = ok;
        }
        f32x4 bias4 = *(const f32x4*)(b2 + q * 4);   // oc = q*4+r

        for (int t8 = 0; t8 < 8; ++t8) {
            int smp = 2 * wv + (t8 >> 2);
            int tt = t8 & 3;                         // conv row-pair (= pooled row)
            int prow = 2 * tt + (n >> 3);
            int pcol = n & 7;
            f32x4 acc = {0.f, 0.f, 0.f, 0.f};
            #pragma unroll
            for (int c = 0; c < 2; ++c) {
                int pb = smp * P1_S + c * 144 + prow * 12 + pcol;
                float fv[8];
                #pragma unroll
                for (int j = 0; j < 8; ++j) {
                    float xv = p1s[pb + offs[j]];
                    fv[j] = vld[j] ? xv : 0.f;
                }
                bf16x8 bh, bl;
                pack_hilo(fv, bh, bl);
                bf16x8 ah = c ? a_h1 : a_h0;
                bf16x8 al = c ? a_l1 : a_l0;
                acc = MFMA16(ah, bh, acc);
                acc = MFMA16(ah, bl, acc);
                acc = MFMA16(al, bh, acc);
            }
            // pool 2x2 via shfl_xor(1: col pair, 8: row pair), bias, relu, write
            #pragma unroll
            for (int r = 0; r < 4; ++r) {
                float vmx = acc[r];
                vmx = fmaxf(vmx, __shfl_xor(vmx, 1, 64));
                vmx = fmaxf(vmx, __shfl_xor(vmx, 8, 64));
                float pv = fmaxf(vmx + bias4[r], 0.f);
                if ((n & 1) == 0 && n < 8) {
                    int jc = n >> 1;
                    hbs[smp * HB_S + (q * 4 + r) * 16 + tt * 4 + jc] = pv;
                }
            }
        }
    }
    __syncthreads();

    // ---- fc1 (split-bf16 MFMA, M-tile per wave) + fc2 partials ----
    {
        const bf16x8* A1h = (const bf16x8*)(ws + A1_HI);
        const bf16x8* A1l = (const bf16x8*)(ws + A1_LO);
        const int abase = (wv * 16 + n) * 32 + q;    // A row m = wv*16+n
        f32x4 acc = {0.f, 0.f, 0.f, 0.f};
        #pragma unroll
        for (int kk = 0; kk < 8; ++kk) {
            bf16x8 ah = A1h[abase + kk * 4];
            bf16x8 al = A1l[abase + kk * 4];
            float fv[8];
            if (n < 8) {
                const f32x4* hp = (const f32x4*)(hbs + n * HB_S + kk * 32 + q * 8);
                f32x4 h0 = hp[0], h1 = hp[1];
                fv[0] = h0.x; fv[1] = h0.y; fv[2] = h0.z; fv[3] = h0.w;
                fv[4] = h1.x; fv[5] = h1.y; fv[6] = h1.z; fv[7] = h1.w;
            } else {
                #pragma unroll
                for (int j = 0; j < 8; ++j) fv[j] = 0.f;
            }
            bf16x8 bh, bl;
            pack_hilo(fv, bh, bl);
            acc = MFMA16(ah, bh, acc);
            acc = MFMA16(ah, bl, acc);
            acc = MFMA16(al, bh, acc);
        }
        // D rows m = wv*16 + q*4 + r, cols n = sample
        f32x4 fb4 = *(const f32x4*)(fb1 + wv * 16 + q * 4);
        f32x4 w20 = *(const f32x4*)(fw2 + wv * 16 + q * 4);
        f32x4 w21 = *(const f32x4*)(fw2 + 64 + wv * 16 + q * 4);
        float p0 = 0.f, p1v = 0.f;
        #pragma unroll
        for (int r = 0; r < 4; ++r) {
            float a = fmaxf(acc[r] + fb4[r], 0.f);
            p0  = fmaf(a, w20[r], p0);
            p1v = fmaf(a, w21[r], p1v);
        }
        p0  += __shfl_xor(p0, 16, 64);  p0  += __shfl_xor(p0, 32, 64);
        p1v += __shfl_xor(p1v, 16, 64); p1v += __shfl_xor(p1v, 32, 64);
        if (q == 0) {
            zbuf[wv * 32 + n * 2]     = p0;
            zbuf[wv * 32 + n * 2 + 1] = p1v;
        }
    }
    __syncthreads();

    // ---- fc2 sum + quantum + fc3 + log_softmax (redundant per-thread tail) ----
    {
        int s = t & 7;
        float x0 = fb2[0] + zbuf[s * 2]     + zbuf[32 + s * 2]
                          + zbuf[64 + s * 2] + zbuf[96 + s * 2];
        float x1 = fb2[1] + zbuf[s * 2 + 1] + zbuf[32 + s * 2 + 1]
                          + zbuf[64 + s * 2 + 1] + zbuf[96 + s * 2 + 1];

        float sr[4], si[4];
        {
            float th0 = -x0 - x1, th1 = -x0 + x1, th2 = x0 - x1, th3 = x0 + x1;
            sr[0] = 0.5f * __cosf(th0); si[0] = 0.5f * __sinf(th0);
            sr[1] = 0.5f * __cosf(th1); si[1] = 0.5f * __sinf(th1);
            sr[2] = 0.5f * __cosf(th2); si[2] = 0.5f * __sinf(th2);
            sr[3] = 0.5f * __cosf(th3); si[3] = 0.5f * __sinf(th3);
        }
        {
            float tr = sr[2]; sr[2] = sr[3]; sr[3] = tr;
            float ti = si[2]; si[2] = si[3]; si[3] = ti;
            float ang = ((float)M_PI - x0) * ((float)M_PI - x1);
            float ca = __cosf(ang), sa = __sinf(ang);
            float r, im;
            r = sr[0]; im = si[0]; sr[0] = r*ca + im*sa; si[0] = im*ca - r*sa;
            r = sr[2]; im = si[2]; sr[2] = r*ca + im*sa; si[2] = im*ca - r*sa;
            r = sr[1]; im = si[1]; sr[1] = r*ca - im*sa; si[1] = im*ca + r*sa;
            r = sr[3]; im = si[3]; sr[3] = r*ca - im*sa; si[3] = im*ca + r*sa;
            tr = sr[2]; sr[2] = sr[3]; sr[3] = tr;
            ti = si[2]; si[2] = si[3]; si[3] = ti;
        }
        float cp[8], sp[8];
        #pragma unroll
        for (int g = 0; g < 8; ++g) { float qv = qp[g]; cp[g] = __cosf(qv); sp[g] = __sinf(qv); }

        #define QRY0(cc, ss) { \
            float a0r=sr[0], a0i=si[0], a1r=sr[2], a1i=si[2]; \
            sr[0]=cc*a0r-ss*a1r; si[0]=cc*a0i-ss*a1i; \
            sr[2]=ss*a0r+cc*a1r; si[2]=ss*a0i+cc*a1i; \
            float b0r=sr[1], b0i=si[1], b1r=sr[3], b1i=si[3]; \
            sr[1]=cc*b0r-ss*b1r; si[1]=cc*b0i-ss*b1i; \
            sr[3]=ss*b0r+cc*b1r; si[3]=ss*b0i+cc*b1i; }
        #define QRY1(cc, ss) { \
            float a0r=sr[0], a0i=si[0], a1r=sr[1], a1i=si[1]; \
            sr[0]=cc*a0r-ss*a1r; si[0]=cc*a0i-ss*a1i; \
            sr[1]=ss*a0r+cc*a1r; si[1]=ss*a0i+cc*a1i; \
            float b0r=sr[2], b0i=si[2], b1r=sr[3], b1i=si[3]; \
            sr[2]=cc*b0r-ss*b1r; si[2]=cc*b0i-ss*b1i; \
            sr[3]=ss*b0r+cc*b1r; si[3]=ss*b0i+cc*b1i; }
        #define QSWAP(i_, j_) { float tr=sr[i_]; sr[i_]=sr[j_]; sr[j_]=tr; \
                                float ti=si[i_]; si[i_]=si[j_]; si[j_]=ti; }

        QRY0(cp[0], sp[0]);
        QRY1(cp[1], sp[1]);
        QSWAP(2, 3);                 // cnot01
        QRY0(cp[2], sp[2]);
        QRY1(cp[3], sp[3]);
        QSWAP(1, 3);                 // cnot10
        QRY0(cp[4], sp[4]);
        QRY1(cp[5], sp[5]);
        QSWAP(2, 3);                 // cnot01
        QRY0(cp[6], sp[6]);
        QRY1(cp[7], sp[7]);

        float qv = (sr[0]*sr[0] + si[0]*si[0])
                 - (sr[1]*sr[1] + si[1]*si[1])
                 - (sr[2]*sr[2] + si[2]*si[2])
                 + (sr[3]*sr[3] + si[3]*si[3]);
        float y = fmaf(qv, fw3[0], fb3[0]);
        float l0 = y, l1 = 1.0f - y;
        float m = fmaxf(l0, l1);
        float lse = m + __logf(__expf(l0 - m) + __expf(l1 - m));
        if (t < 16) {
            int comp = t >> 3;
            out[(base + s) * 2 + comp] = comp ? (l1 - lse) : (l0 - lse);
        }
        #undef QRY0
        #undef QRY1
        #undef QSWAP
    }
}

extern "C" void kernel_launch(void* const* d_in, const int* in_sizes, int n_in,
                              void* d_out, int out_size, void* d_ws, size_t ws_size,
                              hipStream_t stream) {
    const float* x   = (const float*)d_in[0];
    const float* w1  = (const float*)d_in[1];
    const float* b1  = (const float*)d_in[2];
    const float* w2  = (const float*)d_in[3];
    const float* b2  = (const float*)d_in[4];
    const float* fw1 = (const float*)d_in[5];
    const float* fb1 = (const float*)d_in[6];
    const float* fw2 = (const float*)d_in[7];
    const float* fb2 = (const float*)d_in[8];
    const float* fw3 = (const float*)d_in[9];
    const float* fb3 = (const float*)d_in[10];
    const float* qp  = (const float*)d_in[11];
    float* outp = (float*)d_out;
    unsigned short* wsp = (unsigned short*)d_ws;

    hipLaunchKernelGGL(hqcnn_prep, dim3(64), dim3(256), 0, stream, w2, fw1, wsp);

    int B = in_sizes[0] / 784;     // 65536
    int nblk = B / 8;              // 8 samples (4 pairs) per block
    hipLaunchKernelGGL(hqcnn_fused, dim3(nblk), dim3(256), 0, stream,
                       x, w1, b1, b2, fb1, fw2, fb2, fw3, fb3, qp, wsp, outp);
}